// Round 14
// baseline (87.502 us; speedup 1.0000x reference)
//
#include <hip/hip_runtime.h>
#include <math.h>

#define NO 10
#define NFEAT 68
#define HR 5
#define MAXNR 2048
#define MAXLIST 1024
#define MAXNA 256     // max atoms
#define CAP 8         // max entries per (i,j) pair
#define ENTCAP 112    // max staged slots per (atom,half) incl. zero slot
#define NDKMAX 12     // 3 * NK max supported by staged path

// fent[oi*10+oj] = feature index | 256 (if fac==0.5), or -1 if below block-diagonal.
__device__ const int g_fent[100] = {
    256,  1,  2,  3,  4,  5,  6,  7,  8,  9,
     -1,266, 11, 12, 13, 14, 15, 16, 17, 18,
     -1, -1,275,276,277, 28, 29, 30, 31, 32,
     -1, -1,278,279,280, 33, 34, 35, 36, 37,
     -1, -1,281,282,283, 38, 39, 40, 41, 42,
     -1, -1, -1, -1, -1,299,300,301,302,303,
     -1, -1, -1, -1, -1,304,305,306,307,308,
     -1, -1, -1, -1, -1,309,310,311,312,313,
     -1, -1, -1, -1, -1,314,315,316,317,318,
     -1, -1, -1, -1, -1,319,320,321,322,323
};

// Packed feature table (fallback kernel): bits0-3=oi, 4-7=oj, bit8=(fac==0.5)
__device__ const unsigned short g_pk[NFEAT] = {
    0x100, 0x010, 0x020, 0x030, 0x040, 0x050, 0x060, 0x070, 0x080, 0x090,
    0x111, 0x021, 0x031, 0x041, 0x051, 0x061, 0x071, 0x081, 0x091,
    0x122, 0x132, 0x142, 0x123, 0x133, 0x143, 0x124, 0x134, 0x144,
    0x052, 0x062, 0x072, 0x082, 0x092,
    0x053, 0x063, 0x073, 0x083, 0x093,
    0x054, 0x064, 0x074, 0x084, 0x094,
    0x155, 0x165, 0x175, 0x185, 0x195,
    0x156, 0x166, 0x176, 0x186, 0x196,
    0x157, 0x167, 0x177, 0x187, 0x197,
    0x158, 0x168, 0x178, 0x188, 0x198,
    0x159, 0x169, 0x179, 0x189, 0x199
};

// work item idx: [0,E) edge fwd; [E,2E) edge transposed; [2E,2E+N) diag atom.
__device__ __forceinline__ void decode_ab(const int* __restrict__ eidx, int E, int idx,
                                          int& a, int& b) {
    if (idx < E)          { a = eidx[idx];        b = eidx[E + idx]; }
    else if (idx < 2 * E) { int e = idx - E; a = eidx[E + e]; b = eidx[e]; }
    else                  { a = idx - 2 * E; b = a; }
}

// kA: coefE[dk*(E+1)+e] = -v_d*sin(2pi k.R_e) (sentinel e=E -> 1); cnt=0;
// entval[idx*100 + ri*10 + cj] = pre-reduced block values.
__global__ void kA(const float* __restrict__ ecs, const float* __restrict__ kp,
                   const float* __restrict__ ev, const float* __restrict__ ef,
                   const float* __restrict__ nf, float* __restrict__ coefE,
                   int* __restrict__ cnt, float* __restrict__ entval,
                   int E, int N, int NK, int total) {
    int idx0 = blockIdx.x * blockDim.x + threadIdx.x;
    int stride = gridDim.x * blockDim.x;
    const float TWO_PI = 6.283185307179586f;
    int E1 = E + 1;
    int NDK = 3 * NK;
    for (int x = idx0; x < NDK * E1; x += stride) {
        int dk = x / E1, e = x - dk * E1;
        float v;
        if (e == E) v = 1.0f;
        else {
            int d = dk / NK, k = dk - d * NK;
            float th = TWO_PI * (kp[k*3]*ecs[e*3] + kp[k*3+1]*ecs[e*3+1] + kp[k*3+2]*ecs[e*3+2]);
            v = -ev[e * 3 + d] * sinf(th);
        }
        coefE[x] = v;
    }
    for (int x = idx0; x < N * N; x += stride) cnt[x] = 0;
    for (int x = idx0; x < total * 100; x += stride) {
        int pos = x / 100, elem = x - pos * 100;
        int ri = elem / 10, cj = elem - ri * 10;
        float v = 0.f;
        if (pos < E) {
            int fe = g_fent[ri * 10 + cj];
            if (fe >= 0) v = ((fe & 256) ? 0.5f : 1.f) * ef[pos * NFEAT + (fe & 255)];
        } else if (pos < 2 * E) {
            int e = pos - E;
            int fe = g_fent[cj * 10 + ri];
            if (fe >= 0) v = ((fe & 256) ? 0.5f : 1.f) * ef[e * NFEAT + (fe & 255)];
        } else {
            int a = pos - 2 * E;
            int f1 = g_fent[ri * 10 + cj];
            if (f1 >= 0) v += ((f1 & 256) ? 0.5f : 1.f) * nf[a * NFEAT + (f1 & 255)];
            int f2 = g_fent[cj * 10 + ri];
            if (f2 >= 0) v += ((f2 & 256) ? 0.5f : 1.f) * nf[a * NFEAT + (f2 & 255)];
        }
        entval[x] = v;
    }
}

// kB: append work items into dense (a,b) slot lists.
__global__ void kB(const int* __restrict__ eidx, int* __restrict__ cnt,
                   int* __restrict__ ents, int E, int N, int total) {
    int idx = blockIdx.x * blockDim.x + threadIdx.x;
    if (idx >= total) return;
    int a, b; decode_ab(eidx, E, idx, a, b);
    int p = a * N + b;
    int s = atomicAdd(&cnt[p], 1);
    if (s < CAP) ents[p * CAP + s] = idx;
}

// kW4: block (atom i, row-half h). Stage half-blocks + 12-slab coef table ONCE,
// then stream 3*NK slabs x 5 rows with no further barriers (stage:store = 1:12).
__global__ __launch_bounds__(512)
void kW4(const int* __restrict__ cnt, const int* __restrict__ ents,
         const float* __restrict__ entval, const float* __restrict__ coefE,
         float* __restrict__ out, int E, int N, int NK) {
    __shared__ float sRawH[ENTCAP * 50];       // 22.4 KB; slot 0 = zeros
    __shared__ float sCoef[ENTCAP * NDKMAX];   // 5.4 KB;  slot 0 = zeros
    __shared__ int   sEnt[ENTCAP];
    __shared__ int   sSC[MAXNA];               // (start<<5) | cn  (st=0 => zero slot)
    __shared__ int   sCnt;
    const int i = blockIdx.x, h = blockIdx.y;
    const int tid = threadIdx.x, nthr = blockDim.x;
    const int NR = N * NO, E1 = E + 1, twoE = 2 * E;
    const int NDK = 3 * NK;
    const int r0 = h * HR;

    if (tid == 0) sCnt = 1;
    __syncthreads();
    // slot allocation (order-free) + zero slot 0
    for (int j = tid; j < N; j += nthr) {
        int m = min(cnt[i * N + j], CAP);
        if (m > 0) {
            int s = atomicAdd(&sCnt, m);
            sSC[j] = (s <= ENTCAP - m) ? ((s << 5) | m) : (0 << 5 | 1);
        } else sSC[j] = (0 << 5) | 1;
    }
    for (int x = tid; x < 50; x += nthr) sRawH[x] = 0.f;
    for (int x = tid; x < NDKMAX; x += nthr) sCoef[x] = 0.f;
    __syncthreads();
    const int T = sCnt;
    const int n4 = NR >> 2;
    size_t rowbase = (size_t)(i * NO + r0) * NR;

    if (T <= ENTCAP && NDK <= NDKMAX) {
        // ---- stage ----
        for (int j = tid; j < N; j += nthr) {
            int sc = sSC[j], st = sc >> 5, cn = sc & 31;
            if (st > 0)
                for (int y = 0; y < cn; ++y) sEnt[st + y] = ents[(i * N + j) * CAP + y];
        }
        __syncthreads();
        float2* sRaw2 = (float2*)sRawH;
        for (int x = tid; x < (T - 1) * 25; x += nthr) {
            int t = 1 + x / 25, q = x - (x / 25) * 25;
            sRaw2[t * 25 + q] = *(const float2*)(entval + (size_t)sEnt[t] * 100 + r0 * 10 + 2 * q);
        }
        for (int x = tid; x < (T - 1) * NDK; x += nthr) {
            int t = 1 + x / NDK, dk = x - (x / NDK) * NDK;
            int ent = sEnt[t];
            int e = (ent < E) ? ent : ((ent < twoE) ? ent - E : E);
            sCoef[t * NDKMAX + dk] = coefE[dk * E1 + e];
        }
        __syncthreads();
        // ---- stream: 12 slabs x 5 rows, register-cached y=0 fast path ----
        for (int c4 = tid; c4 < n4; c4 += nthr) {
            int st[4], cn[4], cb[4];
            int anym = 0;
#pragma unroll
            for (int t = 0; t < 4; ++t) {
                int ce = 4 * c4 + t, jv = ce / 10;
                cb[t] = ce - jv * 10;
                int sc = sSC[jv];
                st[t] = sc >> 5; cn[t] = sc & 31;
                anym |= (cn[t] > 1);
            }
            if (!anym) {
                float r[HR][4];
#pragma unroll
                for (int ri = 0; ri < HR; ++ri)
#pragma unroll
                    for (int t = 0; t < 4; ++t)
                        r[ri][t] = sRawH[st[t] * 50 + ri * 10 + cb[t]];
                for (int dk = 0; dk < NDK; ++dk) {
                    float cf0 = sCoef[st[0] * NDKMAX + dk];
                    float cf1 = sCoef[st[1] * NDKMAX + dk];
                    float cf2 = sCoef[st[2] * NDKMAX + dk];
                    float cf3 = sCoef[st[3] * NDKMAX + dk];
                    size_t ob = (size_t)dk * NR * NR + rowbase + 4 * c4;
#pragma unroll
                    for (int ri = 0; ri < HR; ++ri)
                        *(float4*)(out + ob + (size_t)ri * NR) =
                            make_float4(r[ri][0]*cf0, r[ri][1]*cf1, r[ri][2]*cf2, r[ri][3]*cf3);
                }
            } else {
                for (int dk = 0; dk < NDK; ++dk) {
                    size_t ob = (size_t)dk * NR * NR + rowbase + 4 * c4;
#pragma unroll
                    for (int ri = 0; ri < HR; ++ri) {
                        float v[4];
#pragma unroll
                        for (int t = 0; t < 4; ++t) {
                            float s = 0.f;
                            for (int y = 0; y < cn[t]; ++y)
                                s += sRawH[(st[t]+y) * 50 + ri * 10 + cb[t]]
                                   * sCoef[(st[t]+y) * NDKMAX + dk];
                            v[t] = s;
                        }
                        *(float4*)(out + ob + (size_t)ri * NR) = make_float4(v[0],v[1],v[2],v[3]);
                    }
                }
            }
        }
    } else {
        // ---- rare fallback: per-element global gather ----
        for (int c4 = tid; c4 < n4; c4 += nthr) {
            int jj[4], cc[4];
#pragma unroll
            for (int t = 0; t < 4; ++t) {
                int ce = 4 * c4 + t, jv = ce / 10;
                jj[t] = jv; cc[t] = ce - jv * 10;
            }
            for (int dk = 0; dk < NDK; ++dk) {
                size_t ob = (size_t)dk * NR * NR + rowbase + 4 * c4;
                for (int ri = 0; ri < HR; ++ri) {
                    float v[4];
#pragma unroll
                    for (int t = 0; t < 4; ++t) {
                        int p = i * N + jj[t];
                        int m = min(cnt[p], CAP);
                        float s = 0.f;
                        for (int y = 0; y < m; ++y) {
                            int ent = ents[p * CAP + y];
                            int e = (ent < E) ? ent : ((ent < twoE) ? ent - E : E);
                            s += entval[(size_t)ent * 100 + (r0 + ri) * 10 + cc[t]]
                               * coefE[dk * E1 + e];
                        }
                        v[t] = s;
                    }
                    *(float4*)(out + ob + (size_t)ri * NR) = make_float4(v[0],v[1],v[2],v[3]);
                }
            }
        }
    }
}

// ---------- fallback (round-7 kernel, 95 us) ----------
__global__ __launch_bounds__(512)
void fused1d(const float* __restrict__ ef, const float* __restrict__ nf,
             const float* __restrict__ ev, const float* __restrict__ ecs,
             const float* __restrict__ kp, const int* __restrict__ eidx,
             float* __restrict__ out,
             int E, int N, int NK, size_t lim) {
    __shared__ float acc[HR * MAXNR];
    __shared__ float coef[MAXLIST];
    __shared__ int   elist[MAXLIST];
    __shared__ int   mcnt;
    const int i = blockIdx.x, k = blockIdx.y;
    const int d = blockIdx.z >> 1, h = blockIdx.z & 1;
    const int r0 = h * HR;
    const int tid = threadIdx.x, nthr = blockDim.x;
    const int NR = N * NO;
    if (NR > MAXNR) return;
    if (tid == 0) mcnt = 0;
    __syncthreads();
    for (int e = tid; e < E; e += nthr) {
        int s = eidx[e], t = eidx[E + e];
        if (s == i) { int p = atomicAdd(&mcnt, 1); if (p < MAXLIST) elist[p] = e * 2; }
        if (t == i) { int p = atomicAdd(&mcnt, 1); if (p < MAXLIST) elist[p] = e * 2 + 1; }
    }
    {
        float4* a4 = (float4*)acc;
        int nz = (HR * NR) >> 2;
        float4 z = make_float4(0.f, 0.f, 0.f, 0.f);
        for (int x = tid; x < nz; x += nthr) a4[x] = z;
    }
    __syncthreads();
    const int m = min(mcnt, MAXLIST);
    const float k0v = kp[k*3], k1v = kp[k*3+1], k2v = kp[k*3+2];
    const float TWO_PI = 6.283185307179586f;
    for (int t = tid; t < m; t += nthr) {
        int e = elist[t] >> 1;
        float th = TWO_PI * (k0v*ecs[e*3] + k1v*ecs[e*3+1] + k2v*ecs[e*3+2]);
        coef[t] = -ev[e*3 + d] * sinf(th);
    }
    __syncthreads();
    const int items = m * NFEAT;
    for (int it = tid; it < items; it += nthr) {
        int t = it / NFEAT, f = it - t * NFEAT;
        int ent = elist[t], e = ent >> 1, dir = ent & 1;
        unsigned pk = g_pk[f];
        int oi = pk & 15, oj = (pk >> 4) & 15;
        int row = dir ? oj : oi, rr = row - r0;
        if ((unsigned)rr < HR) {
            int col = dir ? oi : oj;
            int j = dir ? eidx[e] : eidx[E + e];
            float fac = (pk & 256) ? 0.5f : 1.0f;
            atomicAdd(&acc[rr * NR + j * NO + col], coef[t] * fac * ef[e * NFEAT + f]);
        }
    }
    for (int f = tid; f < NFEAT; f += nthr) {
        unsigned pk = g_pk[f];
        int oi = pk & 15, oj = (pk >> 4) & 15;
        float v = ((pk & 256) ? 0.5f : 1.0f) * nf[i * NFEAT + f];
        int ra = oi - r0, rb = oj - r0;
        if ((unsigned)ra < HR) atomicAdd(&acc[ra * NR + i * NO + oj], v);
        if ((unsigned)rb < HR) atomicAdd(&acc[rb * NR + i * NO + oi], v);
    }
    __syncthreads();
    size_t base = ((size_t)(d * NK + k)) * NR * NR + (size_t)(i * NO + r0) * NR;
    int ntot = HR * NR;
    if ((NR & 3) == 0) {
        const float4* a4 = (const float4*)acc;
        int n4 = ntot >> 2;
        for (int x = tid; x < n4; x += nthr) {
            size_t idx = base + (size_t)x * 4;
            if (idx + 3 < lim) *(float4*)(out + idx) = a4[x];
        }
    } else {
        for (int x = tid; x < ntot; x += nthr) {
            size_t idx = base + x;
            if (idx < lim) out[idx] = acc[x];
        }
    }
}

extern "C" void kernel_launch(void* const* d_in, const int* in_sizes, int n_in,
                              void* d_out, int out_size, void* d_ws, size_t ws_size,
                              hipStream_t stream) {
    const float* ef  = (const float*)d_in[0];
    const float* nf  = (const float*)d_in[1];
    const float* ev  = (const float*)d_in[2];
    const float* ecs = (const float*)d_in[3];
    const float* kp  = (const float*)d_in[4];
    const int*  eidx = (const int*)d_in[5];
    float* out = (float*)d_out;

    int E  = in_sizes[0] / NFEAT;
    int N  = in_sizes[1] / NFEAT;
    int NK = in_sizes[4] / 3;
    int NR = N * NO;
    size_t lim = (size_t)out_size;       // 3*NK*NR*NR floats (real part)
    int total = 2 * E + N;

    // workspace layout
    size_t o = 0;
    auto alloc = [&](size_t bytes) { size_t r = o; o = (o + bytes + 255) & ~(size_t)255; return r; };
    size_t o_coefE  = alloc((size_t)3 * NK * (E + 1) * 4);
    size_t o_cnt    = alloc((size_t)N * N * 4);
    size_t o_ents   = alloc((size_t)N * N * CAP * 4);
    size_t o_entval = alloc((size_t)total * 100 * 4);
    size_t need = o;

    bool ok = (ws_size >= need) && ((NR & 3) == 0) && (N <= MAXNA) &&
              (3 * NK <= NDKMAX) && (lim == (size_t)3 * NK * NR * NR);

    if (!ok) {
        dim3 grid(N, NK, 6);
        fused1d<<<grid, 512, 0, stream>>>(ef, nf, ev, ecs, kp, eidx, out, E, N, NK, lim);
        return;
    }

    char* ws = (char*)d_ws;
    float* coefE  = (float*)(ws + o_coefE);
    int*   cnt    = (int*)(ws + o_cnt);
    int*   ents   = (int*)(ws + o_ents);
    float* entval = (float*)(ws + o_entval);

    kA<<<1024, 256, 0, stream>>>(ecs, kp, ev, ef, nf, coefE, cnt, entval, E, N, NK, total);
    kB<<<(total + 255) / 256, 256, 0, stream>>>(eidx, cnt, ents, E, N, total);
    dim3 gridW(N, 2);
    kW4<<<gridW, 512, 0, stream>>>(cnt, ents, entval, coefE, out, E, N, NK);
}

// Round 15
// 70.710 us; speedup vs baseline: 1.2375x; 1.2375x over previous
//
#include <hip/hip_runtime.h>
#include <math.h>

#define NO 10
#define NFEAT 68
#define HR 5
#define MAXNR 2048
#define MAXLIST 1024
#define MAXNA 256     // max atoms
#define CAP 8         // max entries per (i,j) pair
#define ENTCAP 112    // max staged entries per atom row
#define NKMAX 8

// fent[oi*10+oj] = feature index | 256 (if fac==0.5), or -1 if below block-diagonal.
__device__ const int g_fent[100] = {
    256,  1,  2,  3,  4,  5,  6,  7,  8,  9,
     -1,266, 11, 12, 13, 14, 15, 16, 17, 18,
     -1, -1,275,276,277, 28, 29, 30, 31, 32,
     -1, -1,278,279,280, 33, 34, 35, 36, 37,
     -1, -1,281,282,283, 38, 39, 40, 41, 42,
     -1, -1, -1, -1, -1,299,300,301,302,303,
     -1, -1, -1, -1, -1,304,305,306,307,308,
     -1, -1, -1, -1, -1,309,310,311,312,313,
     -1, -1, -1, -1, -1,314,315,316,317,318,
     -1, -1, -1, -1, -1,319,320,321,322,323
};

// Packed feature table (fallback kernel): bits0-3=oi, 4-7=oj, bit8=(fac==0.5)
__device__ const unsigned short g_pk[NFEAT] = {
    0x100, 0x010, 0x020, 0x030, 0x040, 0x050, 0x060, 0x070, 0x080, 0x090,
    0x111, 0x021, 0x031, 0x041, 0x051, 0x061, 0x071, 0x081, 0x091,
    0x122, 0x132, 0x142, 0x123, 0x133, 0x143, 0x124, 0x134, 0x144,
    0x052, 0x062, 0x072, 0x082, 0x092,
    0x053, 0x063, 0x073, 0x083, 0x093,
    0x054, 0x064, 0x074, 0x084, 0x094,
    0x155, 0x165, 0x175, 0x185, 0x195,
    0x156, 0x166, 0x176, 0x186, 0x196,
    0x157, 0x167, 0x177, 0x187, 0x197,
    0x158, 0x168, 0x178, 0x188, 0x198,
    0x159, 0x169, 0x179, 0x189, 0x199
};

// work item idx: [0,E) edge fwd; [E,2E) edge transposed; [2E,2E+N) diag atom.
__device__ __forceinline__ void decode_ab(const int* __restrict__ eidx, int E, int idx,
                                          int& a, int& b) {
    if (idx < E)          { a = eidx[idx];        b = eidx[E + idx]; }
    else if (idx < 2 * E) { int e = idx - E; a = eidx[E + e]; b = eidx[e]; }
    else                  { a = idx - 2 * E; b = a; }
}

// kA: coefE[dk*(E+1)+e] = -v_d*sin(2pi k.R_e) (sentinel e=E -> 1); cnt=0;
// entval[idx*100 + ri*10 + cj] = pre-reduced block values.
__global__ void kA(const float* __restrict__ ecs, const float* __restrict__ kp,
                   const float* __restrict__ ev, const float* __restrict__ ef,
                   const float* __restrict__ nf, float* __restrict__ coefE,
                   int* __restrict__ cnt, float* __restrict__ entval,
                   int E, int N, int NK, int total) {
    int idx0 = blockIdx.x * blockDim.x + threadIdx.x;
    int stride = gridDim.x * blockDim.x;
    const float TWO_PI = 6.283185307179586f;
    int E1 = E + 1;
    int NDK = 3 * NK;
    for (int x = idx0; x < NDK * E1; x += stride) {
        int dk = x / E1, e = x - dk * E1;
        float v;
        if (e == E) v = 1.0f;
        else {
            int d = dk / NK, k = dk - d * NK;
            float th = TWO_PI * (kp[k*3]*ecs[e*3] + kp[k*3+1]*ecs[e*3+1] + kp[k*3+2]*ecs[e*3+2]);
            v = -ev[e * 3 + d] * sinf(th);
        }
        coefE[x] = v;
    }
    for (int x = idx0; x < N * N; x += stride) cnt[x] = 0;
    for (int x = idx0; x < total * 100; x += stride) {
        int pos = x / 100, elem = x - pos * 100;
        int ri = elem / 10, cj = elem - ri * 10;
        float v = 0.f;
        if (pos < E) {
            int fe = g_fent[ri * 10 + cj];
            if (fe >= 0) v = ((fe & 256) ? 0.5f : 1.f) * ef[pos * NFEAT + (fe & 255)];
        } else if (pos < 2 * E) {
            int e = pos - E;
            int fe = g_fent[cj * 10 + ri];
            if (fe >= 0) v = ((fe & 256) ? 0.5f : 1.f) * ef[e * NFEAT + (fe & 255)];
        } else {
            int a = pos - 2 * E;
            int f1 = g_fent[ri * 10 + cj];
            if (f1 >= 0) v += ((f1 & 256) ? 0.5f : 1.f) * nf[a * NFEAT + (f1 & 255)];
            int f2 = g_fent[cj * 10 + ri];
            if (f2 >= 0) v += ((f2 & 256) ? 0.5f : 1.f) * nf[a * NFEAT + (f2 & 255)];
        }
        entval[x] = v;
    }
}

// kB: append work items into dense (a,b) slot lists.
__global__ void kB(const int* __restrict__ eidx, int* __restrict__ cnt,
                   int* __restrict__ ents, int E, int N, int total) {
    int idx = blockIdx.x * blockDim.x + threadIdx.x;
    if (idx >= total) return;
    int a, b; decode_ab(eidx, E, idx, a, b);
    int p = a * N + b;
    int s = atomicAdd(&cnt[p], 1);
    if (s < CAP) ents[p * CAP + s] = idx;
}

// kW5: block (atom i, direction d) = r13's kW3 geometry, with (a) order-free LDS
// atomic slot allocator (2 barriers instead of 18) and (b) k-OUTER store loop so
// each wave streams one 80KB slab sequentially before moving to the next.
__global__ __launch_bounds__(512)
void kW5(const int* __restrict__ cnt, const int* __restrict__ ents,
         const float* __restrict__ entval, const float* __restrict__ coefE,
         float* __restrict__ out, int E, int N, int NK) {
    __shared__ float sRaw[ENTCAP * 100];     // 44.8 KB
    __shared__ float sCoefT[ENTCAP * NKMAX]; // per-entry per-k coef
    __shared__ int   sEnt[ENTCAP];
    __shared__ int   sSC[MAXNA];             // (start<<5) | cn ; cn==0 -> empty
    __shared__ int   sCnt;
    const int i = blockIdx.x, d = blockIdx.y;
    const int tid = threadIdx.x, nthr = blockDim.x;
    const int NR = N * NO, E1 = E + 1, twoE = 2 * E;
    const int n4 = NR >> 2;

    if (tid == 0) sCnt = 0;
    __syncthreads();
    for (int j = tid; j < N; j += nthr) {
        int m = min(cnt[i * N + j], CAP);
        int sc = 0;
        if (m > 0) {
            int s = atomicAdd(&sCnt, m);
            sc = (s <= ENTCAP - m) ? ((s << 5) | m) : 0;   // overflow -> whole block falls back
        }
        sSC[j] = sc;
    }
    __syncthreads();
    const int T = sCnt;

    if (T <= ENTCAP) {
        // ---- stage: entry ids, raw blocks (float4), per-k coefs ----
        for (int j = tid; j < N; j += nthr) {
            int sc = sSC[j], st = sc >> 5, cn = sc & 31;
            for (int y = 0; y < cn; ++y) sEnt[st + y] = ents[(i * N + j) * CAP + y];
        }
        __syncthreads();
        float4* sRaw4 = (float4*)sRaw;
        for (int x = tid; x < T * 25; x += nthr) {
            int t = x / 25, q = x - t * 25;
            sRaw4[t * 25 + q] = *(const float4*)(entval + (size_t)sEnt[t] * 100 + 4 * q);
        }
        for (int x = tid; x < T * NK; x += nthr) {
            int t = x / NK, k = x - t * NK;
            int ent = sEnt[t];
            int e = (ent < E) ? ent : ((ent < twoE) ? ent - E : E);
            sCoefT[t * NKMAX + k] = coefE[(d * NK + k) * E1 + e];
        }
        __syncthreads();
        // ---- stream: k OUTER, sequential slab sweep, no barriers ----
        for (int k = 0; k < NK; ++k) {
            size_t ob = ((size_t)(d * NK + k) * NR + (size_t)i * NO) * NR;
            for (int c4 = tid; c4 < n4; c4 += nthr) {
                int st[4], cn[4], cb[4];
#pragma unroll
                for (int t = 0; t < 4; ++t) {
                    int ce = 4 * c4 + t, jv = ce / 10, cc = ce - jv * 10;
                    int sc = sSC[jv];
                    st[t] = sc >> 5; cn[t] = sc & 31; cb[t] = cc;
                }
#pragma unroll
                for (int ri = 0; ri < NO; ++ri) {
                    float v[4];
#pragma unroll
                    for (int t = 0; t < 4; ++t) {
                        float s = 0.f;
                        for (int y = 0; y < cn[t]; ++y)
                            s += sRaw[(st[t] + y) * 100 + ri * 10 + cb[t]]
                               * sCoefT[(st[t] + y) * NKMAX + k];
                        v[t] = s;
                    }
                    *(float4*)(out + ob + (size_t)ri * NR + 4 * c4) =
                        make_float4(v[0], v[1], v[2], v[3]);
                }
            }
        }
    } else {
        // ---- rare fallback: per-element global gather ----
        for (int k = 0; k < NK; ++k) {
            size_t ob = ((size_t)(d * NK + k) * NR + (size_t)i * NO) * NR;
            for (int c4 = tid; c4 < n4; c4 += nthr) {
                int jj[4], cc[4];
#pragma unroll
                for (int t = 0; t < 4; ++t) {
                    int ce = 4 * c4 + t, jv = ce / 10;
                    jj[t] = jv; cc[t] = ce - jv * 10;
                }
                for (int ri = 0; ri < NO; ++ri) {
                    float v[4];
#pragma unroll
                    for (int t = 0; t < 4; ++t) {
                        int p = i * N + jj[t];
                        int m = min(cnt[p], CAP);
                        float s = 0.f;
                        for (int y = 0; y < m; ++y) {
                            int ent = ents[p * CAP + y];
                            int e = (ent < E) ? ent : ((ent < twoE) ? ent - E : E);
                            s += entval[(size_t)ent * 100 + ri * 10 + cc[t]]
                               * coefE[(d * NK + k) * E1 + e];
                        }
                        v[t] = s;
                    }
                    *(float4*)(out + ob + (size_t)ri * NR + 4 * c4) =
                        make_float4(v[0], v[1], v[2], v[3]);
                }
            }
        }
    }
}

// ---------- fallback (round-7 kernel, 95 us) ----------
__global__ __launch_bounds__(512)
void fused1d(const float* __restrict__ ef, const float* __restrict__ nf,
             const float* __restrict__ ev, const float* __restrict__ ecs,
             const float* __restrict__ kp, const int* __restrict__ eidx,
             float* __restrict__ out,
             int E, int N, int NK, size_t lim) {
    __shared__ float acc[HR * MAXNR];
    __shared__ float coef[MAXLIST];
    __shared__ int   elist[MAXLIST];
    __shared__ int   mcnt;
    const int i = blockIdx.x, k = blockIdx.y;
    const int d = blockIdx.z >> 1, h = blockIdx.z & 1;
    const int r0 = h * HR;
    const int tid = threadIdx.x, nthr = blockDim.x;
    const int NR = N * NO;
    if (NR > MAXNR) return;
    if (tid == 0) mcnt = 0;
    __syncthreads();
    for (int e = tid; e < E; e += nthr) {
        int s = eidx[e], t = eidx[E + e];
        if (s == i) { int p = atomicAdd(&mcnt, 1); if (p < MAXLIST) elist[p] = e * 2; }
        if (t == i) { int p = atomicAdd(&mcnt, 1); if (p < MAXLIST) elist[p] = e * 2 + 1; }
    }
    {
        float4* a4 = (float4*)acc;
        int nz = (HR * NR) >> 2;
        float4 z = make_float4(0.f, 0.f, 0.f, 0.f);
        for (int x = tid; x < nz; x += nthr) a4[x] = z;
    }
    __syncthreads();
    const int m = min(mcnt, MAXLIST);
    const float k0v = kp[k*3], k1v = kp[k*3+1], k2v = kp[k*3+2];
    const float TWO_PI = 6.283185307179586f;
    for (int t = tid; t < m; t += nthr) {
        int e = elist[t] >> 1;
        float th = TWO_PI * (k0v*ecs[e*3] + k1v*ecs[e*3+1] + k2v*ecs[e*3+2]);
        coef[t] = -ev[e*3 + d] * sinf(th);
    }
    __syncthreads();
    const int items = m * NFEAT;
    for (int it = tid; it < items; it += nthr) {
        int t = it / NFEAT, f = it - t * NFEAT;
        int ent = elist[t], e = ent >> 1, dir = ent & 1;
        unsigned pk = g_pk[f];
        int oi = pk & 15, oj = (pk >> 4) & 15;
        int row = dir ? oj : oi, rr = row - r0;
        if ((unsigned)rr < HR) {
            int col = dir ? oi : oj;
            int j = dir ? eidx[e] : eidx[E + e];
            float fac = (pk & 256) ? 0.5f : 1.0f;
            atomicAdd(&acc[rr * NR + j * NO + col], coef[t] * fac * ef[e * NFEAT + f]);
        }
    }
    for (int f = tid; f < NFEAT; f += nthr) {
        unsigned pk = g_pk[f];
        int oi = pk & 15, oj = (pk >> 4) & 15;
        float v = ((pk & 256) ? 0.5f : 1.0f) * nf[i * NFEAT + f];
        int ra = oi - r0, rb = oj - r0;
        if ((unsigned)ra < HR) atomicAdd(&acc[ra * NR + i * NO + oj], v);
        if ((unsigned)rb < HR) atomicAdd(&acc[rb * NR + i * NO + oi], v);
    }
    __syncthreads();
    size_t base = ((size_t)(d * NK + k)) * NR * NR + (size_t)(i * NO + r0) * NR;
    int ntot = HR * NR;
    if ((NR & 3) == 0) {
        const float4* a4 = (const float4*)acc;
        int n4 = ntot >> 2;
        for (int x = tid; x < n4; x += nthr) {
            size_t idx = base + (size_t)x * 4;
            if (idx + 3 < lim) *(float4*)(out + idx) = a4[x];
        }
    } else {
        for (int x = tid; x < ntot; x += nthr) {
            size_t idx = base + x;
            if (idx < lim) out[idx] = acc[x];
        }
    }
}

extern "C" void kernel_launch(void* const* d_in, const int* in_sizes, int n_in,
                              void* d_out, int out_size, void* d_ws, size_t ws_size,
                              hipStream_t stream) {
    const float* ef  = (const float*)d_in[0];
    const float* nf  = (const float*)d_in[1];
    const float* ev  = (const float*)d_in[2];
    const float* ecs = (const float*)d_in[3];
    const float* kp  = (const float*)d_in[4];
    const int*  eidx = (const int*)d_in[5];
    float* out = (float*)d_out;

    int E  = in_sizes[0] / NFEAT;
    int N  = in_sizes[1] / NFEAT;
    int NK = in_sizes[4] / 3;
    int NR = N * NO;
    size_t lim = (size_t)out_size;       // 3*NK*NR*NR floats (real part)
    int total = 2 * E + N;

    // workspace layout
    size_t o = 0;
    auto alloc = [&](size_t bytes) { size_t r = o; o = (o + bytes + 255) & ~(size_t)255; return r; };
    size_t o_coefE  = alloc((size_t)3 * NK * (E + 1) * 4);
    size_t o_cnt    = alloc((size_t)N * N * 4);
    size_t o_ents   = alloc((size_t)N * N * CAP * 4);
    size_t o_entval = alloc((size_t)total * 100 * 4);
    size_t need = o;

    bool ok = (ws_size >= need) && ((NR & 3) == 0) && (N <= MAXNA) && (NK <= NKMAX) &&
              (lim == (size_t)3 * NK * NR * NR);

    if (!ok) {
        dim3 grid(N, NK, 6);
        fused1d<<<grid, 512, 0, stream>>>(ef, nf, ev, ecs, kp, eidx, out, E, N, NK, lim);
        return;
    }

    char* ws = (char*)d_ws;
    float* coefE  = (float*)(ws + o_coefE);
    int*   cnt    = (int*)(ws + o_cnt);
    int*   ents   = (int*)(ws + o_ents);
    float* entval = (float*)(ws + o_entval);

    kA<<<1024, 256, 0, stream>>>(ecs, kp, ev, ef, nf, coefE, cnt, entval, E, N, NK, total);
    kB<<<(total + 255) / 256, 256, 0, stream>>>(eidx, cnt, ents, E, N, total);
    dim3 gridW(N, 3);
    kW5<<<gridW, 512, 0, stream>>>(cnt, ents, entval, coefE, out, E, N, NK);
}